// Round 14
// baseline (102.360 us; speedup 1.0000x reference)
//
#include <hip/hip_runtime.h>
#include <hip/hip_bf16.h>
#include <math.h>

#define BB 32
#define SS 4096
#define DHH 512
#define EHH 512
#define AA 256

typedef __attribute__((ext_vector_type(8))) short bf16x8;
typedef __attribute__((ext_vector_type(4))) float f32x4;

__device__ __forceinline__ short f2bf(float f) {
    unsigned u = __float_as_uint(f);
    u += 0x7FFFu + ((u >> 16) & 1u);   // RNE
    return (short)(u >> 16);
}

__device__ __forceinline__ unsigned cvt2bf(float a, float b) {
    __hip_bfloat162 h = __float22bfloat162_rn(float2{a, b});  // v_cvt_pk_bf16_f32
    return *(unsigned*)&h;
}

__device__ __forceinline__ float tanh_fast(float x) {
    float e = __expf(2.0f * x);
    return 1.0f - 2.0f * __builtin_amdgcn_rcpf(e + 1.0f);
}

// K0: pack We (E,A) fp32 -> fragment-major bf16, coalesced reads.
__global__ __launch_bounds__(256) void k_packWe(const float* __restrict__ We,
                                                unsigned short* __restrict__ Wpack) {
    int tid = threadIdx.x;
    int e = blockIdx.x * 4 + (tid >> 6);
    int a4 = (tid & 63) * 4;
    float4 t = *(const float4*)&We[(size_t)e * AA + a4];
    int kk = e >> 5, hi = (e >> 3) & 3, j = e & 7;
    const float* tf = (const float*)&t;
    #pragma unroll
    for (int u = 0; u < 4; ++u) {
        int a = a4 + u;
        int ct = a >> 4, lo = a & 15;
        Wpack[((size_t)((kk * 16 + ct) * 64 + hi * 16 + lo)) * 8 + j] = (unsigned short)f2bf(tf[u]);
    }
}

// K1: dec_proj partials, 8-way K-split
__global__ __launch_bounds__(256) void k_decproj(const float* __restrict__ h,
                                                 const float* __restrict__ Wd,
                                                 float* __restrict__ dp8) {
    int b = blockIdx.x, sp = blockIdx.y;
    int a = threadIdx.x;
    const float* hb = h + (size_t)b * DHH + sp * 64;
    const float* wb = Wd + (size_t)(sp * 64) * AA + a;
    float acc = 0.f;
    #pragma unroll 16
    for (int i = 0; i < 64; ++i)
        acc = fmaf(hb[i], wb[(size_t)i * AA], acc);
    dp8[((size_t)b * 8 + sp) * AA + a] = acc;
}

// K2: fused energy GEMM + local softmax stats + partial context.
// R14: 32-row chunks, 512 thr (8 waves), wave w: all 32 rows x cols w*32..+32.
// LDS 33KB -> 4 blocks/CU (LDS); __launch_bounds__(512,6) targets 6 waves/SIMD
// (vs 4 in R9-R13) -- the single variable under test is resident TLP.
__global__ __launch_bounds__(512, 6) void k_energy_mfma(const float* __restrict__ enc,
                                                        const unsigned short* __restrict__ Wpack,
                                                        const float* __restrict__ dp8,
                                                        const float* __restrict__ v,
                                                        const int* __restrict__ mask,
                                                        float* __restrict__ energy,
                                                        float* __restrict__ pctx,
                                                        float2* __restrict__ ml) {
    __shared__ unsigned short Abuf[8][32 * 64];   // 8 regions x 4KB = 32 KB
    __shared__ float part[8][32];                 // 1 KB

    int bk = blockIdx.x;            // 4096 = 32 b * 128 chunks
    int b  = bk >> 7;
    int chunk = bk & 127;
    int s0 = chunk * 32;
    int tid = threadIdx.x;
    int l  = tid & 63;
    int w  = tid >> 6;              // 0..7
    int lo = l & 15;
    int hi = l >> 4;

    // ---- phase 1: flat-contiguous staging, 2 batches of 4 float4 (VGPR economy) ----
    // float4 flat f = j*2048 + i*512 + tid; row = f>>7, col4 = f&127
    const float4* gS = (const float4*)(enc + ((size_t)b * SS + s0) * EHH);
    #pragma unroll
    for (int j = 0; j < 2; ++j) {
        float4 st[4];
        #pragma unroll
        for (int i = 0; i < 4; ++i)
            st[i] = gS[j * 2048 + i * 512 + tid];
        #pragma unroll
        for (int i = 0; i < 4; ++i) {
            int f = j * 2048 + i * 512 + tid;
            int row = f >> 7;
            int col4 = f & 127;
            int ktS = col4 >> 4;
            int cb = (col4 & 15) * 8;
            uint2 wv = { cvt2bf(st[i].x, st[i].y), cvt2bf(st[i].z, st[i].w) };
            *(uint2*)((char*)Abuf[ktS] + ((row * 128 + cb) ^ ((row & 7) << 4))) = wv;
        }
    }
    __syncthreads();

    // ---- phase 2: barrier-free MFMA loop, B 2-deep prefetch from L2 ----
    f32x4 acc[2][2];
    #pragma unroll
    for (int rt = 0; rt < 2; ++rt)
        #pragma unroll
        for (int ct = 0; ct < 2; ++ct)
            acc[rt][ct] = (f32x4){0.f, 0.f, 0.f, 0.f};

    const unsigned short* bbase = Wpack + ((size_t)(w * 2) * 64 + l) * 8;  // + g*8192 + ct*512
    bf16x8 bn0[2], bn1[2];
    #pragma unroll
    for (int ct = 0; ct < 2; ++ct) bn0[ct] = *(const bf16x8*)(bbase + ct * 512);
    #pragma unroll
    for (int ct = 0; ct < 2; ++ct) bn1[ct] = *(const bf16x8*)(bbase + 8192 + ct * 512);

    #pragma unroll
    for (int g = 0; g < 16; ++g) {          // g = kt*2 + ks
        int kt = g >> 1, ks = g & 1;
        bf16x8 bcur[2];
        #pragma unroll
        for (int ct = 0; ct < 2; ++ct) { bcur[ct] = bn0[ct]; bn0[ct] = bn1[ct]; }
        if (g + 2 < 16) {
            const unsigned short* bp = bbase + (size_t)(g + 2) * 8192;
            #pragma unroll
            for (int ct = 0; ct < 2; ++ct)
                bn1[ct] = *(const bf16x8*)(bp + ct * 512);
        }
        const char* lb = (const char*)Abuf[kt];
        bf16x8 afr[2];
        #pragma unroll
        for (int rt = 0; rt < 2; ++rt) {
            int row = rt * 16 + lo;
            afr[rt] = *(const bf16x8*)(lb + ((row * 128 + ks * 64 + hi * 16) ^ ((row & 7) << 4)));
        }
        #pragma unroll
        for (int rt = 0; rt < 2; ++rt)
            #pragma unroll
            for (int ct = 0; ct < 2; ++ct)
                acc[rt][ct] = __builtin_amdgcn_mfma_f32_16x16x32_bf16(afr[rt], bcur[ct], acc[rt][ct], 0, 0, 0);
    }

    // ---- energy epilogue: partial row-sums over this wave's 32 cols ----
    float ps[2][4];
    #pragma unroll
    for (int rt = 0; rt < 2; ++rt)
        #pragma unroll
        for (int rr = 0; rr < 4; ++rr) ps[rt][rr] = 0.f;
    #pragma unroll
    for (int ct = 0; ct < 2; ++ct) {
        int n = w * 32 + ct * 16 + lo;
        float dpv = 0.f;
        #pragma unroll
        for (int sp = 0; sp < 8; ++sp)
            dpv += dp8[((size_t)b * 8 + sp) * AA + n];
        float vv = v[n];
        #pragma unroll
        for (int rt = 0; rt < 2; ++rt)
            #pragma unroll
            for (int rr = 0; rr < 4; ++rr)
                ps[rt][rr] += vv * tanh_fast(acc[rt][ct][rr] + dpv);
    }
    #pragma unroll
    for (int off = 1; off < 16; off <<= 1)
        #pragma unroll
        for (int rt = 0; rt < 2; ++rt)
            #pragma unroll
            for (int rr = 0; rr < 4; ++rr)
                ps[rt][rr] += __shfl_xor(ps[rt][rr], off);
    if (lo == 0) {
        #pragma unroll
        for (int rt = 0; rt < 2; ++rt)
            #pragma unroll
            for (int rr = 0; rr < 4; ++rr)
                part[w][rt * 16 + 4 * hi + rr] = ps[rt][rr];
    }
    __syncthreads();

    // ---- stats: all waves redundantly; lane l -> row l&31 (width-32 reduce) ----
    float e = 0.f;
    #pragma unroll
    for (int i = 0; i < 8; ++i) e += part[i][l & 31];
    if (w == 0 && l < 32) energy[(size_t)b * SS + s0 + l] = e;
    int mk = mask[(size_t)b * SS + s0 + (l & 31)];
    float val = mk ? e : -INFINITY;
    float m = val;
    #pragma unroll
    for (int off = 1; off < 32; off <<= 1) m = fmaxf(m, __shfl_xor(m, off));
    float wgt = (val == -INFINITY) ? 0.f : __expf(val - m);
    float lsum = wgt;
    #pragma unroll
    for (int off = 1; off < 32; off <<= 1) lsum += __shfl_xor(lsum, off);
    if (w == 0 && l == 0) ml[(size_t)b * 128 + chunk] = float2{m, lsum};

    // ---- partial context: wave w owns region w (4 ds_read_b128/lane + shfl) ----
    // lane: col-chunk cc = l&7 (8 bf16 cols), row-group rg = l>>3 (4 rows each)
    {
        int cc = l & 7;
        int rg = l >> 3;
        const char* lb = (const char*)Abuf[w];
        float acc8[8];
        #pragma unroll
        for (int jj = 0; jj < 8; ++jj) acc8[jj] = 0.f;
        #pragma unroll
        for (int i = 0; i < 4; ++i) {
            int row = rg * 4 + i;
            float wr = __shfl(wgt, row);
            bf16x8 u = *(const bf16x8*)(lb + row * 128 + ((cc * 16) ^ ((row & 7) << 4)));
            #pragma unroll
            for (int jj = 0; jj < 8; ++jj)
                acc8[jj] = fmaf(wr, __uint_as_float(((unsigned)(unsigned short)u[jj]) << 16), acc8[jj]);
        }
        #pragma unroll
        for (int off = 8; off < 64; off <<= 1)
            #pragma unroll
            for (int jj = 0; jj < 8; ++jj)
                acc8[jj] += __shfl_xor(acc8[jj], off);
        if (l < 8) {
            float* dst = &pctx[((size_t)(b * 128 + chunk)) * 512 + w * 64 + cc * 8];
            *(float4*)dst = (float4){acc8[0], acc8[1], acc8[2], acc8[3]};
            *(float4*)(dst + 4) = (float4){acc8[4], acc8[5], acc8[6], acc8[7]};
        }
    }
}

// K3: fused final softmax (attn) + context, 128 chunks. Grid (B, 4), 512 thr.
__global__ __launch_bounds__(512) void k_final(const float* __restrict__ energy,
                                               const int* __restrict__ mask,
                                               const float2* __restrict__ ml,
                                               const float* __restrict__ pctx,
                                               float* __restrict__ attn,
                                               float* __restrict__ ctx) {
    __shared__ float wm[8], wz[8];
    __shared__ float scal[128];
    __shared__ float red[4][128];
    int b = blockIdx.x, sl = blockIdx.y;
    int tid = threadIdx.x;
    int l = tid & 63, w = tid >> 6;

    float2 p = float2{-INFINITY, 0.f};
    if (tid < 128) p = ml[(size_t)b * 128 + tid];
    float m = p.x;
    #pragma unroll
    for (int off = 1; off < 64; off <<= 1) m = fmaxf(m, __shfl_xor(m, off));
    if (!l) wm[w] = m;
    __syncthreads();
    float M = wm[0];
    #pragma unroll
    for (int i = 1; i < 8; ++i) M = fmaxf(M, wm[i]);
    float sc = (p.x == -INFINITY) ? 0.f : __expf(p.x - M);
    if (tid < 128) scal[tid] = sc;
    float z = sc * p.y;
    #pragma unroll
    for (int off = 1; off < 64; off <<= 1) z += __shfl_xor(z, off);
    if (!l) wz[w] = z;
    __syncthreads();
    float Z = 0.f;
    #pragma unroll
    for (int i = 0; i < 8; ++i) Z += wz[i];
    float invZ = (Z > 0.f) ? 1.0f / Z : 0.f;

    #pragma unroll
    for (int it = 0; it < 2; ++it) {
        int s = sl * 1024 + it * 512 + tid;
        float e = energy[(size_t)b * SS + s];
        int mk = mask[(size_t)b * SS + s];
        attn[(size_t)b * SS + s] = mk ? __expf(e - M) * invZ : 0.f;
    }

    {
        int cg = tid >> 7;            // 0..3
        int e  = sl * 128 + (tid & 127);
        float acc = 0.f;
        #pragma unroll 8
        for (int i = 0; i < 32; ++i) {
            int c = cg * 32 + i;
            acc = fmaf(scal[c], pctx[((size_t)(b * 128 + c)) * 512 + e], acc);
        }
        red[cg][tid & 127] = acc;
    }
    __syncthreads();
    if (tid < 128) {
        float s = red[0][tid] + red[1][tid] + red[2][tid] + red[3][tid];
        ctx[(size_t)b * EHH + sl * 128 + tid] = s * invZ;
    }
}

extern "C" void kernel_launch(void* const* d_in, const int* in_sizes, int n_in,
                              void* d_out, int out_size, void* d_ws, size_t ws_size,
                              hipStream_t stream) {
    const float* h    = (const float*)d_in[0];
    const float* enc  = (const float*)d_in[1];
    const int*   mask = (const int*)d_in[2];
    const float* Wd   = (const float*)d_in[3];
    const float* We   = (const float*)d_in[4];
    const float* v    = (const float*)d_in[5];

    float* out  = (float*)d_out;
    float* ctx  = out;              // (B, EH)
    float* attn = out + BB * EHH;   // (B, S)

    char* ws = (char*)d_ws;
    float*          dp8    = (float*)ws;                          // 256 KB
    float*          energy = (float*)(ws + (256 << 10));          // 512 KB
    unsigned short* Wpack  = (unsigned short*)(ws + (768 << 10)); // 256 KB
    float*          pctx   = (float*)(ws + (1 << 20));            // 8 MB
    float2*         ml     = (float2*)(ws + (9 << 20));           // 32 KB

    k_packWe<<<128, 256, 0, stream>>>(We, Wpack);
    k_decproj<<<dim3(BB, 8), AA, 0, stream>>>(h, Wd, dp8);
    k_energy_mfma<<<BB * SS / 32, 512, 0, stream>>>(enc, Wpack, dp8, v, mask,
                                                    energy, pctx, ml);
    k_final<<<dim3(BB, 4), 512, 0, stream>>>(energy, mask, ml, pctx, attn, ctx);
}

// Round 15
// 89.964 us; speedup vs baseline: 1.1378x; 1.1378x over previous
//
#include <hip/hip_runtime.h>
#include <hip/hip_bf16.h>
#include <math.h>

#define BB 32
#define SS 4096
#define DHH 512
#define EHH 512
#define AA 256

typedef __attribute__((ext_vector_type(8))) short bf16x8;
typedef __attribute__((ext_vector_type(4))) float f32x4;

__device__ __forceinline__ short f2bf(float f) {
    unsigned u = __float_as_uint(f);
    u += 0x7FFFu + ((u >> 16) & 1u);   // RNE
    return (short)(u >> 16);
}

__device__ __forceinline__ unsigned cvt2bf(float a, float b) {
    __hip_bfloat162 h = __float22bfloat162_rn(float2{a, b});  // v_cvt_pk_bf16_f32
    return *(unsigned*)&h;
}

__device__ __forceinline__ float tanh_fast(float x) {
    float e = __expf(2.0f * x);
    return 1.0f - 2.0f * __builtin_amdgcn_rcpf(e + 1.0f);
}

// K0 (merged prologue): blocks 0..127 pack We -> fragment-major bf16 (coalesced);
// blocks 128..383 compute dec_proj 8-way K-split partials. No cross-role dep.
__global__ __launch_bounds__(256) void k_prologue(const float* __restrict__ We,
                                                  const float* __restrict__ h,
                                                  const float* __restrict__ Wd,
                                                  unsigned short* __restrict__ Wpack,
                                                  float* __restrict__ dp8) {
    int blk = blockIdx.x;
    int tid = threadIdx.x;
    if (blk < 128) {
        // pack We: Wpack[((kk*16+ct)*64 + hi*16+lo)*8 + j] = We[k][n]
        int e = blk * 4 + (tid >> 6);
        int a4 = (tid & 63) * 4;
        float4 t = *(const float4*)&We[(size_t)e * AA + a4];
        int kk = e >> 5, hi = (e >> 3) & 3, j = e & 7;
        const float* tf = (const float*)&t;
        #pragma unroll
        for (int u = 0; u < 4; ++u) {
            int a = a4 + u;
            int ct = a >> 4, lo = a & 15;
            Wpack[((size_t)((kk * 16 + ct) * 64 + hi * 16 + lo)) * 8 + j] =
                (unsigned short)f2bf(tf[u]);
        }
    } else {
        int idx = blk - 128;        // 256 blocks = 32 b x 8 splits
        int b = idx >> 3, sp = idx & 7;
        int a = tid;
        const float* hb = h + (size_t)b * DHH + sp * 64;
        const float* wb = Wd + (size_t)(sp * 64) * AA + a;
        float acc = 0.f;
        #pragma unroll 16
        for (int i = 0; i < 64; ++i)
            acc = fmaf(hb[i], wb[(size_t)i * AA], acc);
        dp8[((size_t)b * 8 + sp) * AA + a] = acc;
    }
}

// K2: fused energy GEMM + local softmax stats + partial context (R12 structure:
// 64-row chunks, 512 thr/8 waves, single-barrier flat staging, B 2-deep prefetch,
// wave w = all 64 rows x cols w*32..+32, pctx via 8x ds_read_b128 + shfl reduce).
__global__ __launch_bounds__(512, 4) void k_energy_mfma(const float* __restrict__ enc,
                                                        const unsigned short* __restrict__ Wpack,
                                                        const float* __restrict__ dp8,
                                                        const float* __restrict__ v,
                                                        const int* __restrict__ mask,
                                                        float* __restrict__ energy,
                                                        float* __restrict__ pctx,
                                                        float2* __restrict__ ml) {
    __shared__ unsigned short Abuf[8][64 * 64];   // 8 regions x 8KB, swizzled bf16
    __shared__ float part[8][64];                 // 2 KB

    int bk = blockIdx.x;            // 2048 = 32 b * 64 chunks
    int b  = bk >> 6;
    int chunk = bk & 63;
    int s0 = chunk * 64;
    int tid = threadIdx.x;
    int l  = tid & 63;
    int w  = tid >> 6;              // 0..7
    int lo = l & 15;
    int hi = l >> 4;

    // ---- phase 1: staging (thread -> row r, 8-float group q), 1 barrier ----
    int r = tid >> 3;
    int q = tid & 7;
    const float* gbase = enc + ((size_t)b * SS + s0 + r) * EHH + q * 8;
    int wb0 = ((r * 128 + q * 16) ^ ((r & 7) << 4));

    float4 sva[8], svb[8];
    #pragma unroll
    for (int kt = 0; kt < 8; ++kt) {
        const float4* gp = (const float4*)(gbase + kt * 64);
        sva[kt] = gp[0]; svb[kt] = gp[1];
    }
    #pragma unroll
    for (int kt = 0; kt < 8; ++kt) {
        uint4 w0 = { cvt2bf(sva[kt].x, sva[kt].y), cvt2bf(sva[kt].z, sva[kt].w),
                     cvt2bf(svb[kt].x, svb[kt].y), cvt2bf(svb[kt].z, svb[kt].w) };
        *(uint4*)((char*)Abuf[kt] + wb0) = w0;
    }
    __syncthreads();

    // ---- phase 2: barrier-free MFMA loop, B 2-deep prefetch from L2 ----
    f32x4 acc[4][2];
    #pragma unroll
    for (int rt = 0; rt < 4; ++rt)
        #pragma unroll
        for (int ct = 0; ct < 2; ++ct)
            acc[rt][ct] = (f32x4){0.f, 0.f, 0.f, 0.f};

    const unsigned short* bbase = Wpack + ((size_t)(w * 2) * 64 + l) * 8;  // + g*8192 + ct*512
    bf16x8 bn0[2], bn1[2];
    #pragma unroll
    for (int ct = 0; ct < 2; ++ct) bn0[ct] = *(const bf16x8*)(bbase + ct * 512);
    #pragma unroll
    for (int ct = 0; ct < 2; ++ct) bn1[ct] = *(const bf16x8*)(bbase + 8192 + ct * 512);

    #pragma unroll
    for (int g = 0; g < 16; ++g) {          // g = kt*2 + ks
        int kt = g >> 1, ks = g & 1;
        bf16x8 bcur[2];
        #pragma unroll
        for (int ct = 0; ct < 2; ++ct) { bcur[ct] = bn0[ct]; bn0[ct] = bn1[ct]; }
        if (g + 2 < 16) {
            const unsigned short* bp = bbase + (size_t)(g + 2) * 8192;
            #pragma unroll
            for (int ct = 0; ct < 2; ++ct)
                bn1[ct] = *(const bf16x8*)(bp + ct * 512);
        }
        const char* lb = (const char*)Abuf[kt];
        bf16x8 afr[4];
        #pragma unroll
        for (int rt = 0; rt < 4; ++rt) {
            int row = rt * 16 + lo;
            afr[rt] = *(const bf16x8*)(lb + ((row * 128 + ks * 64 + hi * 16) ^ ((row & 7) << 4)));
        }
        #pragma unroll
        for (int rt = 0; rt < 4; ++rt)
            #pragma unroll
            for (int ct = 0; ct < 2; ++ct)
                acc[rt][ct] = __builtin_amdgcn_mfma_f32_16x16x32_bf16(afr[rt], bcur[ct], acc[rt][ct], 0, 0, 0);
    }

    // ---- energy epilogue: partial row-sums over this wave's 32 cols ----
    float ps[4][4];
    #pragma unroll
    for (int rt = 0; rt < 4; ++rt)
        #pragma unroll
        for (int rr = 0; rr < 4; ++rr) ps[rt][rr] = 0.f;
    #pragma unroll
    for (int ct = 0; ct < 2; ++ct) {
        int n = w * 32 + ct * 16 + lo;
        float dpv = 0.f;
        #pragma unroll
        for (int sp = 0; sp < 8; ++sp)
            dpv += dp8[((size_t)b * 8 + sp) * AA + n];
        float vv = v[n];
        #pragma unroll
        for (int rt = 0; rt < 4; ++rt)
            #pragma unroll
            for (int rr = 0; rr < 4; ++rr)
                ps[rt][rr] += vv * tanh_fast(acc[rt][ct][rr] + dpv);
    }
    #pragma unroll
    for (int off = 1; off < 16; off <<= 1)
        #pragma unroll
        for (int rt = 0; rt < 4; ++rt)
            #pragma unroll
            for (int rr = 0; rr < 4; ++rr)
                ps[rt][rr] += __shfl_xor(ps[rt][rr], off);
    if (lo == 0) {
        #pragma unroll
        for (int rt = 0; rt < 4; ++rt)
            #pragma unroll
            for (int rr = 0; rr < 4; ++rr)
                part[w][rt * 16 + 4 * hi + rr] = ps[rt][rr];
    }
    __syncthreads();

    // ---- stats: all waves redundantly (lane = row) ----
    float e = 0.f;
    #pragma unroll
    for (int i = 0; i < 8; ++i) e += part[i][l];
    if (w == 0) energy[(size_t)b * SS + s0 + l] = e;
    int mk = mask[(size_t)b * SS + s0 + l];
    float val = mk ? e : -INFINITY;
    float m = val;
    #pragma unroll
    for (int off = 1; off < 64; off <<= 1) m = fmaxf(m, __shfl_xor(m, off));
    float wgt = (val == -INFINITY) ? 0.f : __expf(val - m);
    float lsum = wgt;
    #pragma unroll
    for (int off = 1; off < 64; off <<= 1) lsum += __shfl_xor(lsum, off);
    if (w == 0 && l == 0) ml[(size_t)b * 64 + chunk] = float2{m, lsum};

    // ---- partial context: wave w owns LDS region w; 8 ds_read_b128/lane + shfl ----
    {
        int cc = l & 7;
        int rg = l >> 3;
        const char* lb = (const char*)Abuf[w];
        float acc8[8];
        #pragma unroll
        for (int jj = 0; jj < 8; ++jj) acc8[jj] = 0.f;
        #pragma unroll
        for (int i = 0; i < 8; ++i) {
            int row = rg * 8 + i;
            float wr = __shfl(wgt, row);
            bf16x8 u = *(const bf16x8*)(lb + row * 128 + ((cc * 16) ^ (i << 4)));
            #pragma unroll
            for (int jj = 0; jj < 8; ++jj)
                acc8[jj] = fmaf(wr, __uint_as_float(((unsigned)(unsigned short)u[jj]) << 16), acc8[jj]);
        }
        #pragma unroll
        for (int off = 8; off < 64; off <<= 1)
            #pragma unroll
            for (int jj = 0; jj < 8; ++jj)
                acc8[jj] += __shfl_xor(acc8[jj], off);
        if (l < 8) {
            float* dst = &pctx[((size_t)(b * 64 + chunk)) * 512 + w * 64 + cc * 8];
            *(float4*)dst = (float4){acc8[0], acc8[1], acc8[2], acc8[3]};
            *(float4*)(dst + 4) = (float4){acc8[4], acc8[5], acc8[6], acc8[7]};
        }
    }
}

// K3: fused final softmax (attn) + context. Grid (B, 4 slices), 512 thr.
__global__ __launch_bounds__(512) void k_final(const float* __restrict__ energy,
                                               const int* __restrict__ mask,
                                               const float2* __restrict__ ml,
                                               const float* __restrict__ pctx,
                                               float* __restrict__ attn,
                                               float* __restrict__ ctx) {
    __shared__ float scal[64];
    __shared__ float sM, sZ;
    __shared__ float red[4][128];
    int b = blockIdx.x, sl = blockIdx.y;
    int tid = threadIdx.x;

    if (tid < 64) {                 // wave 0: chunk stats (64 chunks)
        float2 p = ml[(size_t)b * 64 + tid];
        float m = p.x;
        #pragma unroll
        for (int off = 1; off < 64; off <<= 1) m = fmaxf(m, __shfl_xor(m, off));
        float sc = (p.x == -INFINITY) ? 0.f : __expf(p.x - m);
        scal[tid] = sc;
        float z = sc * p.y;
        #pragma unroll
        for (int off = 1; off < 64; off <<= 1) z += __shfl_xor(z, off);
        if (tid == 0) { sM = m; sZ = z; }
    }
    __syncthreads();
    float M = sM;
    float invZ = (sZ > 0.f) ? 1.0f / sZ : 0.f;

    #pragma unroll
    for (int it = 0; it < 2; ++it) {
        int s = sl * 1024 + it * 512 + tid;
        float e = energy[(size_t)b * SS + s];
        int mk = mask[(size_t)b * SS + s];
        attn[(size_t)b * SS + s] = mk ? __expf(e - M) * invZ : 0.f;
    }

    {
        int cg = tid >> 7;            // 0..3
        int e  = sl * 128 + (tid & 127);
        float acc = 0.f;
        #pragma unroll 8
        for (int i = 0; i < 16; ++i) {
            int c = cg * 16 + i;
            acc = fmaf(scal[c], pctx[((size_t)(b * 64 + c)) * 512 + e], acc);
        }
        red[cg][tid & 127] = acc;
    }
    __syncthreads();
    if (tid < 128) {
        float s = red[0][tid] + red[1][tid] + red[2][tid] + red[3][tid];
        ctx[(size_t)b * EHH + sl * 128 + tid] = s * invZ;
    }
}

extern "C" void kernel_launch(void* const* d_in, const int* in_sizes, int n_in,
                              void* d_out, int out_size, void* d_ws, size_t ws_size,
                              hipStream_t stream) {
    const float* h    = (const float*)d_in[0];
    const float* enc  = (const float*)d_in[1];
    const int*   mask = (const int*)d_in[2];
    const float* Wd   = (const float*)d_in[3];
    const float* We   = (const float*)d_in[4];
    const float* v    = (const float*)d_in[5];

    float* out  = (float*)d_out;
    float* ctx  = out;              // (B, EH)
    float* attn = out + BB * EHH;   // (B, S)

    char* ws = (char*)d_ws;
    float*          dp8    = (float*)ws;                          // 256 KB
    float*          energy = (float*)(ws + (256 << 10));          // 512 KB
    unsigned short* Wpack  = (unsigned short*)(ws + (768 << 10)); // 256 KB
    float*          pctx   = (float*)(ws + (1 << 20));            // 4 MB
    float2*         ml     = (float2*)(ws + (6 << 20));           // 16 KB

    k_prologue<<<384, 256, 0, stream>>>(We, h, Wd, Wpack, dp8);
    k_energy_mfma<<<BB * SS / 64, 512, 0, stream>>>(enc, Wpack, dp8, v, mask,
                                                    energy, pctx, ml);
    k_final<<<dim3(BB, 4), 512, 0, stream>>>(energy, mask, ml, pctx, attn, ctx);
}

// Round 16
// 89.789 us; speedup vs baseline: 1.1400x; 1.0020x over previous
//
#include <hip/hip_runtime.h>
#include <hip/hip_bf16.h>
#include <math.h>

#define BB 32
#define SS 4096
#define DHH 512
#define EHH 512
#define AA 256

typedef __attribute__((ext_vector_type(8))) short bf16x8;
typedef __attribute__((ext_vector_type(4))) float f32x4;

__device__ __forceinline__ short f2bf(float f) {
    unsigned u = __float_as_uint(f);
    u += 0x7FFFu + ((u >> 16) & 1u);   // RNE
    return (short)(u >> 16);
}

__device__ __forceinline__ unsigned cvt2bf(float a, float b) {
    __hip_bfloat162 h = __float22bfloat162_rn(float2{a, b});  // v_cvt_pk_bf16_f32
    return *(unsigned*)&h;
}

__device__ __forceinline__ float tanh_fast(float x) {
    float e = __expf(2.0f * x);
    return 1.0f - 2.0f * __builtin_amdgcn_rcpf(e + 1.0f);
}

// K0 (merged prologue): blocks 0..127 pack We -> fragment-major bf16 (coalesced);
// blocks 128..383 compute dec_proj 8-way K-split partials.
__global__ __launch_bounds__(256) void k_prologue(const float* __restrict__ We,
                                                  const float* __restrict__ h,
                                                  const float* __restrict__ Wd,
                                                  unsigned short* __restrict__ Wpack,
                                                  float* __restrict__ dp8) {
    int blk = blockIdx.x;
    int tid = threadIdx.x;
    if (blk < 128) {
        int e = blk * 4 + (tid >> 6);
        int a4 = (tid & 63) * 4;
        float4 t = *(const float4*)&We[(size_t)e * AA + a4];
        int kk = e >> 5, hi = (e >> 3) & 3, j = e & 7;
        const float* tf = (const float*)&t;
        #pragma unroll
        for (int u = 0; u < 4; ++u) {
            int a = a4 + u;
            int ct = a >> 4, lo = a & 15;
            Wpack[((size_t)((kk * 16 + ct) * 64 + hi * 16 + lo)) * 8 + j] =
                (unsigned short)f2bf(tf[u]);
        }
    } else {
        int idx = blk - 128;        // 256 blocks = 32 b x 8 splits
        int b = idx >> 3, sp = idx & 7;
        int a = tid;
        const float* hb = h + (size_t)b * DHH + sp * 64;
        const float* wb = Wd + (size_t)(sp * 64) * AA + a;
        float acc = 0.f;
        #pragma unroll 16
        for (int i = 0; i < 64; ++i)
            acc = fmaf(hb[i], wb[(size_t)i * AA], acc);
        dp8[((size_t)b * 8 + sp) * AA + a] = acc;
    }
}

// K2: fused energy GEMM + local softmax stats + partial context.
// R15 structure; R16 changes ONLY: (a) staging in 4 batches of 4 float4
// (live staging VGPRs 64->16), (b) B prefetch deepened 2->3 g-steps
// (~270cy lookahead > ~200cy L2 latency; removes per-g vmcnt stall).
__global__ __launch_bounds__(512, 4) void k_energy_mfma(const float* __restrict__ enc,
                                                        const unsigned short* __restrict__ Wpack,
                                                        const float* __restrict__ dp8,
                                                        const float* __restrict__ v,
                                                        const int* __restrict__ mask,
                                                        float* __restrict__ energy,
                                                        float* __restrict__ pctx,
                                                        float2* __restrict__ ml) {
    __shared__ unsigned short Abuf[8][64 * 64];   // 8 regions x 8KB, swizzled bf16
    __shared__ float part[8][64];                 // 2 KB

    int bk = blockIdx.x;            // 2048 = 32 b * 64 chunks
    int b  = bk >> 6;
    int chunk = bk & 63;
    int s0 = chunk * 64;
    int tid = threadIdx.x;
    int l  = tid & 63;
    int w  = tid >> 6;              // 0..7
    int lo = l & 15;
    int hi = l >> 4;

    // ---- phase 1: staging in 4 batches of 4 float4 (thread -> row r, group q) ----
    int r = tid >> 3;
    int q = tid & 7;
    const float* gbase = enc + ((size_t)b * SS + s0 + r) * EHH + q * 8;
    int wb0 = ((r * 128 + q * 16) ^ ((r & 7) << 4));

    #pragma unroll
    for (int bt = 0; bt < 4; ++bt) {
        float4 sa0, sb0, sa1, sb1;
        {
            const float4* gp = (const float4*)(gbase + (bt * 2) * 64);
            sa0 = gp[0]; sb0 = gp[1];
        }
        {
            const float4* gp = (const float4*)(gbase + (bt * 2 + 1) * 64);
            sa1 = gp[0]; sb1 = gp[1];
        }
        uint4 w0 = { cvt2bf(sa0.x, sa0.y), cvt2bf(sa0.z, sa0.w),
                     cvt2bf(sb0.x, sb0.y), cvt2bf(sb0.z, sb0.w) };
        *(uint4*)((char*)Abuf[bt * 2] + wb0) = w0;
        uint4 w1 = { cvt2bf(sa1.x, sa1.y), cvt2bf(sa1.z, sa1.w),
                     cvt2bf(sb1.x, sb1.y), cvt2bf(sb1.z, sb1.w) };
        *(uint4*)((char*)Abuf[bt * 2 + 1] + wb0) = w1;
    }
    __syncthreads();

    // ---- phase 2: barrier-free MFMA loop, B 3-deep prefetch from L2 ----
    f32x4 acc[4][2];
    #pragma unroll
    for (int rt = 0; rt < 4; ++rt)
        #pragma unroll
        for (int ct = 0; ct < 2; ++ct)
            acc[rt][ct] = (f32x4){0.f, 0.f, 0.f, 0.f};

    const unsigned short* bbase = Wpack + ((size_t)(w * 2) * 64 + l) * 8;  // + g*8192 + ct*512
    bf16x8 bn0[2], bn1[2], bn2[2];
    #pragma unroll
    for (int ct = 0; ct < 2; ++ct) bn0[ct] = *(const bf16x8*)(bbase + ct * 512);
    #pragma unroll
    for (int ct = 0; ct < 2; ++ct) bn1[ct] = *(const bf16x8*)(bbase + 8192 + ct * 512);
    #pragma unroll
    for (int ct = 0; ct < 2; ++ct) bn2[ct] = *(const bf16x8*)(bbase + 16384 + ct * 512);

    #pragma unroll
    for (int g = 0; g < 16; ++g) {          // g = kt*2 + ks
        int kt = g >> 1, ks = g & 1;
        bf16x8 bcur[2];
        #pragma unroll
        for (int ct = 0; ct < 2; ++ct) {
            bcur[ct] = bn0[ct];
            bn0[ct] = bn1[ct];
            bn1[ct] = bn2[ct];
        }
        if (g + 3 < 16) {
            const unsigned short* bp = bbase + (size_t)(g + 3) * 8192;
            #pragma unroll
            for (int ct = 0; ct < 2; ++ct)
                bn2[ct] = *(const bf16x8*)(bp + ct * 512);
        }
        const char* lb = (const char*)Abuf[kt];
        bf16x8 afr[4];
        #pragma unroll
        for (int rt = 0; rt < 4; ++rt) {
            int row = rt * 16 + lo;
            afr[rt] = *(const bf16x8*)(lb + ((row * 128 + ks * 64 + hi * 16) ^ ((row & 7) << 4)));
        }
        #pragma unroll
        for (int rt = 0; rt < 4; ++rt)
            #pragma unroll
            for (int ct = 0; ct < 2; ++ct)
                acc[rt][ct] = __builtin_amdgcn_mfma_f32_16x16x32_bf16(afr[rt], bcur[ct], acc[rt][ct], 0, 0, 0);
    }

    // ---- energy epilogue: partial row-sums over this wave's 32 cols ----
    float ps[4][4];
    #pragma unroll
    for (int rt = 0; rt < 4; ++rt)
        #pragma unroll
        for (int rr = 0; rr < 4; ++rr) ps[rt][rr] = 0.f;
    #pragma unroll
    for (int ct = 0; ct < 2; ++ct) {
        int n = w * 32 + ct * 16 + lo;
        float dpv = 0.f;
        #pragma unroll
        for (int sp = 0; sp < 8; ++sp)
            dpv += dp8[((size_t)b * 8 + sp) * AA + n];
        float vv = v[n];
        #pragma unroll
        for (int rt = 0; rt < 4; ++rt)
            #pragma unroll
            for (int rr = 0; rr < 4; ++rr)
                ps[rt][rr] += vv * tanh_fast(acc[rt][ct][rr] + dpv);
    }
    #pragma unroll
    for (int off = 1; off < 16; off <<= 1)
        #pragma unroll
        for (int rt = 0; rt < 4; ++rt)
            #pragma unroll
            for (int rr = 0; rr < 4; ++rr)
                ps[rt][rr] += __shfl_xor(ps[rt][rr], off);
    if (lo == 0) {
        #pragma unroll
        for (int rt = 0; rt < 4; ++rt)
            #pragma unroll
            for (int rr = 0; rr < 4; ++rr)
                part[w][rt * 16 + 4 * hi + rr] = ps[rt][rr];
    }
    __syncthreads();

    // ---- stats: all waves redundantly (lane = row) ----
    float e = 0.f;
    #pragma unroll
    for (int i = 0; i < 8; ++i) e += part[i][l];
    if (w == 0) energy[(size_t)b * SS + s0 + l] = e;
    int mk = mask[(size_t)b * SS + s0 + l];
    float val = mk ? e : -INFINITY;
    float m = val;
    #pragma unroll
    for (int off = 1; off < 64; off <<= 1) m = fmaxf(m, __shfl_xor(m, off));
    float wgt = (val == -INFINITY) ? 0.f : __expf(val - m);
    float lsum = wgt;
    #pragma unroll
    for (int off = 1; off < 64; off <<= 1) lsum += __shfl_xor(lsum, off);
    if (w == 0 && l == 0) ml[(size_t)b * 64 + chunk] = float2{m, lsum};

    // ---- partial context: wave w owns LDS region w; 8 ds_read_b128/lane + shfl ----
    {
        int cc = l & 7;
        int rg = l >> 3;
        const char* lb = (const char*)Abuf[w];
        float acc8[8];
        #pragma unroll
        for (int jj = 0; jj < 8; ++jj) acc8[jj] = 0.f;
        #pragma unroll
        for (int i = 0; i < 8; ++i) {
            int row = rg * 8 + i;
            float wr = __shfl(wgt, row);
            bf16x8 u = *(const bf16x8*)(lb + row * 128 + ((cc * 16) ^ (i << 4)));
            #pragma unroll
            for (int jj = 0; jj < 8; ++jj)
                acc8[jj] = fmaf(wr, __uint_as_float(((unsigned)(unsigned short)u[jj]) << 16), acc8[jj]);
        }
        #pragma unroll
        for (int off = 8; off < 64; off <<= 1)
            #pragma unroll
            for (int jj = 0; jj < 8; ++jj)
                acc8[jj] += __shfl_xor(acc8[jj], off);
        if (l < 8) {
            float* dst = &pctx[((size_t)(b * 64 + chunk)) * 512 + w * 64 + cc * 8];
            *(float4*)dst = (float4){acc8[0], acc8[1], acc8[2], acc8[3]};
            *(float4*)(dst + 4) = (float4){acc8[4], acc8[5], acc8[6], acc8[7]};
        }
    }
}

// K3: fused final softmax (attn) + context. Grid (B, 4 slices), 512 thr.
__global__ __launch_bounds__(512) void k_final(const float* __restrict__ energy,
                                               const int* __restrict__ mask,
                                               const float2* __restrict__ ml,
                                               const float* __restrict__ pctx,
                                               float* __restrict__ attn,
                                               float* __restrict__ ctx) {
    __shared__ float scal[64];
    __shared__ float sM, sZ;
    __shared__ float red[4][128];
    int b = blockIdx.x, sl = blockIdx.y;
    int tid = threadIdx.x;

    if (tid < 64) {                 // wave 0: chunk stats (64 chunks)
        float2 p = ml[(size_t)b * 64 + tid];
        float m = p.x;
        #pragma unroll
        for (int off = 1; off < 64; off <<= 1) m = fmaxf(m, __shfl_xor(m, off));
        float sc = (p.x == -INFINITY) ? 0.f : __expf(p.x - m);
        scal[tid] = sc;
        float z = sc * p.y;
        #pragma unroll
        for (int off = 1; off < 64; off <<= 1) z += __shfl_xor(z, off);
        if (tid == 0) { sM = m; sZ = z; }
    }
    __syncthreads();
    float M = sM;
    float invZ = (sZ > 0.f) ? 1.0f / sZ : 0.f;

    #pragma unroll
    for (int it = 0; it < 2; ++it) {
        int s = sl * 1024 + it * 512 + tid;
        float e = energy[(size_t)b * SS + s];
        int mk = mask[(size_t)b * SS + s];
        attn[(size_t)b * SS + s] = mk ? __expf(e - M) * invZ : 0.f;
    }

    {
        int cg = tid >> 7;            // 0..3
        int e  = sl * 128 + (tid & 127);
        float acc = 0.f;
        #pragma unroll 8
        for (int i = 0; i < 16; ++i) {
            int c = cg * 16 + i;
            acc = fmaf(scal[c], pctx[((size_t)(b * 64 + c)) * 512 + e], acc);
        }
        red[cg][tid & 127] = acc;
    }
    __syncthreads();
    if (tid < 128) {
        float s = red[0][tid] + red[1][tid] + red[2][tid] + red[3][tid];
        ctx[(size_t)b * EHH + sl * 128 + tid] = s * invZ;
    }
}

extern "C" void kernel_launch(void* const* d_in, const int* in_sizes, int n_in,
                              void* d_out, int out_size, void* d_ws, size_t ws_size,
                              hipStream_t stream) {
    const float* h    = (const float*)d_in[0];
    const float* enc  = (const float*)d_in[1];
    const int*   mask = (const int*)d_in[2];
    const float* Wd   = (const float*)d_in[3];
    const float* We   = (const float*)d_in[4];
    const float* v    = (const float*)d_in[5];

    float* out  = (float*)d_out;
    float* ctx  = out;              // (B, EH)
    float* attn = out + BB * EHH;   // (B, S)

    char* ws = (char*)d_ws;
    float*          dp8    = (float*)ws;                          // 256 KB
    float*          energy = (float*)(ws + (256 << 10));          // 512 KB
    unsigned short* Wpack  = (unsigned short*)(ws + (768 << 10)); // 256 KB
    float*          pctx   = (float*)(ws + (1 << 20));            // 4 MB
    float2*         ml     = (float2*)(ws + (6 << 20));           // 16 KB

    k_prologue<<<384, 256, 0, stream>>>(We, h, Wd, Wpack, dp8);
    k_energy_mfma<<<BB * SS / 64, 512, 0, stream>>>(enc, Wpack, dp8, v, mask,
                                                    energy, pctx, ml);
    k_final<<<dim3(BB, 4), 512, 0, stream>>>(energy, mask, ml, pctx, attn, ctx);
}

// Round 17
// 89.231 us; speedup vs baseline: 1.1471x; 1.0063x over previous
//
#include <hip/hip_runtime.h>
#include <hip/hip_bf16.h>
#include <math.h>

#define BB 32
#define SS 4096
#define DHH 512
#define EHH 512
#define AA 256

typedef __attribute__((ext_vector_type(8))) short bf16x8;
typedef __attribute__((ext_vector_type(4))) float f32x4;

__device__ __forceinline__ short f2bf(float f) {
    unsigned u = __float_as_uint(f);
    u += 0x7FFFu + ((u >> 16) & 1u);   // RNE
    return (short)(u >> 16);
}

__device__ __forceinline__ unsigned cvt2bf(float a, float b) {
    __hip_bfloat162 h = __float22bfloat162_rn(float2{a, b});  // v_cvt_pk_bf16_f32
    return *(unsigned*)&h;
}

__device__ __forceinline__ float tanh_fast(float x) {
    float e = __expf(2.0f * x);
    return 1.0f - 2.0f * __builtin_amdgcn_rcpf(e + 1.0f);
}

// K0 (merged prologue): blocks 0..127 pack We -> fragment-major bf16 (coalesced);
// blocks 128..383 compute dec_proj 8-way K-split partials.
__global__ __launch_bounds__(256) void k_prologue(const float* __restrict__ We,
                                                  const float* __restrict__ h,
                                                  const float* __restrict__ Wd,
                                                  unsigned short* __restrict__ Wpack,
                                                  float* __restrict__ dp8) {
    int blk = blockIdx.x;
    int tid = threadIdx.x;
    if (blk < 128) {
        int e = blk * 4 + (tid >> 6);
        int a4 = (tid & 63) * 4;
        float4 t = *(const float4*)&We[(size_t)e * AA + a4];
        int kk = e >> 5, hi = (e >> 3) & 3, j = e & 7;
        const float* tf = (const float*)&t;
        #pragma unroll
        for (int u = 0; u < 4; ++u) {
            int a = a4 + u;
            int ct = a >> 4, lo = a & 15;
            Wpack[((size_t)((kk * 16 + ct) * 64 + hi * 16 + lo)) * 8 + j] =
                (unsigned short)f2bf(tf[u]);
        }
    } else {
        int idx = blk - 128;        // 256 blocks = 32 b x 8 splits
        int b = idx >> 3, sp = idx & 7;
        int a = tid;
        const float* hb = h + (size_t)b * DHH + sp * 64;
        const float* wb = Wd + (size_t)(sp * 64) * AA + a;
        float acc = 0.f;
        #pragma unroll 16
        for (int i = 0; i < 64; ++i)
            acc = fmaf(hb[i], wb[(size_t)i * AA], acc);
        dp8[((size_t)b * 8 + sp) * AA + a] = acc;
    }
}

// K2: fused energy GEMM + local softmax stats + partial context.
// R16 structure; R17 change ONLY: s_setprio(1) around the MFMA loop (T5) --
// with 2 blocks/CU at staggered phases, MFMA-phase waves win SIMD arbitration
// over staging-phase waves.
__global__ __launch_bounds__(512, 4) void k_energy_mfma(const float* __restrict__ enc,
                                                        const unsigned short* __restrict__ Wpack,
                                                        const float* __restrict__ dp8,
                                                        const float* __restrict__ v,
                                                        const int* __restrict__ mask,
                                                        float* __restrict__ energy,
                                                        float* __restrict__ pctx,
                                                        float2* __restrict__ ml) {
    __shared__ unsigned short Abuf[8][64 * 64];   // 8 regions x 8KB, swizzled bf16
    __shared__ float part[8][64];                 // 2 KB

    int bk = blockIdx.x;            // 2048 = 32 b * 64 chunks
    int b  = bk >> 6;
    int chunk = bk & 63;
    int s0 = chunk * 64;
    int tid = threadIdx.x;
    int l  = tid & 63;
    int w  = tid >> 6;              // 0..7
    int lo = l & 15;
    int hi = l >> 4;

    // ---- phase 1: staging in 4 batches of 4 float4 (thread -> row r, group q) ----
    int r = tid >> 3;
    int q = tid & 7;
    const float* gbase = enc + ((size_t)b * SS + s0 + r) * EHH + q * 8;
    int wb0 = ((r * 128 + q * 16) ^ ((r & 7) << 4));

    #pragma unroll
    for (int bt = 0; bt < 4; ++bt) {
        float4 sa0, sb0, sa1, sb1;
        {
            const float4* gp = (const float4*)(gbase + (bt * 2) * 64);
            sa0 = gp[0]; sb0 = gp[1];
        }
        {
            const float4* gp = (const float4*)(gbase + (bt * 2 + 1) * 64);
            sa1 = gp[0]; sb1 = gp[1];
        }
        uint4 w0 = { cvt2bf(sa0.x, sa0.y), cvt2bf(sa0.z, sa0.w),
                     cvt2bf(sb0.x, sb0.y), cvt2bf(sb0.z, sb0.w) };
        *(uint4*)((char*)Abuf[bt * 2] + wb0) = w0;
        uint4 w1 = { cvt2bf(sa1.x, sa1.y), cvt2bf(sa1.z, sa1.w),
                     cvt2bf(sb1.x, sb1.y), cvt2bf(sb1.z, sb1.w) };
        *(uint4*)((char*)Abuf[bt * 2 + 1] + wb0) = w1;
    }
    __syncthreads();

    // ---- phase 2: barrier-free MFMA loop, B 3-deep prefetch, setprio(1) ----
    f32x4 acc[4][2];
    #pragma unroll
    for (int rt = 0; rt < 4; ++rt)
        #pragma unroll
        for (int ct = 0; ct < 2; ++ct)
            acc[rt][ct] = (f32x4){0.f, 0.f, 0.f, 0.f};

    const unsigned short* bbase = Wpack + ((size_t)(w * 2) * 64 + l) * 8;  // + g*8192 + ct*512
    bf16x8 bn0[2], bn1[2], bn2[2];
    #pragma unroll
    for (int ct = 0; ct < 2; ++ct) bn0[ct] = *(const bf16x8*)(bbase + ct * 512);
    #pragma unroll
    for (int ct = 0; ct < 2; ++ct) bn1[ct] = *(const bf16x8*)(bbase + 8192 + ct * 512);
    #pragma unroll
    for (int ct = 0; ct < 2; ++ct) bn2[ct] = *(const bf16x8*)(bbase + 16384 + ct * 512);

    __builtin_amdgcn_s_setprio(1);
    #pragma unroll
    for (int g = 0; g < 16; ++g) {          // g = kt*2 + ks
        int kt = g >> 1, ks = g & 1;
        bf16x8 bcur[2];
        #pragma unroll
        for (int ct = 0; ct < 2; ++ct) {
            bcur[ct] = bn0[ct];
            bn0[ct] = bn1[ct];
            bn1[ct] = bn2[ct];
        }
        if (g + 3 < 16) {
            const unsigned short* bp = bbase + (size_t)(g + 3) * 8192;
            #pragma unroll
            for (int ct = 0; ct < 2; ++ct)
                bn2[ct] = *(const bf16x8*)(bp + ct * 512);
        }
        const char* lb = (const char*)Abuf[kt];
        bf16x8 afr[4];
        #pragma unroll
        for (int rt = 0; rt < 4; ++rt) {
            int row = rt * 16 + lo;
            afr[rt] = *(const bf16x8*)(lb + ((row * 128 + ks * 64 + hi * 16) ^ ((row & 7) << 4)));
        }
        #pragma unroll
        for (int rt = 0; rt < 4; ++rt)
            #pragma unroll
            for (int ct = 0; ct < 2; ++ct)
                acc[rt][ct] = __builtin_amdgcn_mfma_f32_16x16x32_bf16(afr[rt], bcur[ct], acc[rt][ct], 0, 0, 0);
    }
    __builtin_amdgcn_s_setprio(0);

    // ---- energy epilogue: partial row-sums over this wave's 32 cols ----
    float ps[4][4];
    #pragma unroll
    for (int rt = 0; rt < 4; ++rt)
        #pragma unroll
        for (int rr = 0; rr < 4; ++rr) ps[rt][rr] = 0.f;
    #pragma unroll
    for (int ct = 0; ct < 2; ++ct) {
        int n = w * 32 + ct * 16 + lo;
        float dpv = 0.f;
        #pragma unroll
        for (int sp = 0; sp < 8; ++sp)
            dpv += dp8[((size_t)b * 8 + sp) * AA + n];
        float vv = v[n];
        #pragma unroll
        for (int rt = 0; rt < 4; ++rt)
            #pragma unroll
            for (int rr = 0; rr < 4; ++rr)
                ps[rt][rr] += vv * tanh_fast(acc[rt][ct][rr] + dpv);
    }
    #pragma unroll
    for (int off = 1; off < 16; off <<= 1)
        #pragma unroll
        for (int rt = 0; rt < 4; ++rt)
            #pragma unroll
            for (int rr = 0; rr < 4; ++rr)
                ps[rt][rr] += __shfl_xor(ps[rt][rr], off);
    if (lo == 0) {
        #pragma unroll
        for (int rt = 0; rt < 4; ++rt)
            #pragma unroll
            for (int rr = 0; rr < 4; ++rr)
                part[w][rt * 16 + 4 * hi + rr] = ps[rt][rr];
    }
    __syncthreads();

    // ---- stats: all waves redundantly (lane = row) ----
    float e = 0.f;
    #pragma unroll
    for (int i = 0; i < 8; ++i) e += part[i][l];
    if (w == 0) energy[(size_t)b * SS + s0 + l] = e;
    int mk = mask[(size_t)b * SS + s0 + l];
    float val = mk ? e : -INFINITY;
    float m = val;
    #pragma unroll
    for (int off = 1; off < 64; off <<= 1) m = fmaxf(m, __shfl_xor(m, off));
    float wgt = (val == -INFINITY) ? 0.f : __expf(val - m);
    float lsum = wgt;
    #pragma unroll
    for (int off = 1; off < 64; off <<= 1) lsum += __shfl_xor(lsum, off);
    if (w == 0 && l == 0) ml[(size_t)b * 64 + chunk] = float2{m, lsum};

    // ---- partial context: wave w owns LDS region w; 8 ds_read_b128/lane + shfl ----
    {
        int cc = l & 7;
        int rg = l >> 3;
        const char* lb = (const char*)Abuf[w];
        float acc8[8];
        #pragma unroll
        for (int jj = 0; jj < 8; ++jj) acc8[jj] = 0.f;
        #pragma unroll
        for (int i = 0; i < 8; ++i) {
            int row = rg * 8 + i;
            float wr = __shfl(wgt, row);
            bf16x8 u = *(const bf16x8*)(lb + row * 128 + ((cc * 16) ^ (i << 4)));
            #pragma unroll
            for (int jj = 0; jj < 8; ++jj)
                acc8[jj] = fmaf(wr, __uint_as_float(((unsigned)(unsigned short)u[jj]) << 16), acc8[jj]);
        }
        #pragma unroll
        for (int off = 8; off < 64; off <<= 1)
            #pragma unroll
            for (int jj = 0; jj < 8; ++jj)
                acc8[jj] += __shfl_xor(acc8[jj], off);
        if (l < 8) {
            float* dst = &pctx[((size_t)(b * 64 + chunk)) * 512 + w * 64 + cc * 8];
            *(float4*)dst = (float4){acc8[0], acc8[1], acc8[2], acc8[3]};
            *(float4*)(dst + 4) = (float4){acc8[4], acc8[5], acc8[6], acc8[7]};
        }
    }
}

// K3: fused final softmax (attn) + context. Grid (B, 4 slices), 512 thr.
__global__ __launch_bounds__(512) void k_final(const float* __restrict__ energy,
                                               const int* __restrict__ mask,
                                               const float2* __restrict__ ml,
                                               const float* __restrict__ pctx,
                                               float* __restrict__ attn,
                                               float* __restrict__ ctx) {
    __shared__ float scal[64];
    __shared__ float sM, sZ;
    __shared__ float red[4][128];
    int b = blockIdx.x, sl = blockIdx.y;
    int tid = threadIdx.x;

    if (tid < 64) {                 // wave 0: chunk stats (64 chunks)
        float2 p = ml[(size_t)b * 64 + tid];
        float m = p.x;
        #pragma unroll
        for (int off = 1; off < 64; off <<= 1) m = fmaxf(m, __shfl_xor(m, off));
        float sc = (p.x == -INFINITY) ? 0.f : __expf(p.x - m);
        scal[tid] = sc;
        float z = sc * p.y;
        #pragma unroll
        for (int off = 1; off < 64; off <<= 1) z += __shfl_xor(z, off);
        if (tid == 0) { sM = m; sZ = z; }
    }
    __syncthreads();
    float M = sM;
    float invZ = (sZ > 0.f) ? 1.0f / sZ : 0.f;

    #pragma unroll
    for (int it = 0; it < 2; ++it) {
        int s = sl * 1024 + it * 512 + tid;
        float e = energy[(size_t)b * SS + s];
        int mk = mask[(size_t)b * SS + s];
        attn[(size_t)b * SS + s] = mk ? __expf(e - M) * invZ : 0.f;
    }

    {
        int cg = tid >> 7;            // 0..3
        int e  = sl * 128 + (tid & 127);
        float acc = 0.f;
        #pragma unroll 8
        for (int i = 0; i < 16; ++i) {
            int c = cg * 16 + i;
            acc = fmaf(scal[c], pctx[((size_t)(b * 64 + c)) * 512 + e], acc);
        }
        red[cg][tid & 127] = acc;
    }
    __syncthreads();
    if (tid < 128) {
        float s = red[0][tid] + red[1][tid] + red[2][tid] + red[3][tid];
        ctx[(size_t)b * EHH + sl * 128 + tid] = s * invZ;
    }
}

extern "C" void kernel_launch(void* const* d_in, const int* in_sizes, int n_in,
                              void* d_out, int out_size, void* d_ws, size_t ws_size,
                              hipStream_t stream) {
    const float* h    = (const float*)d_in[0];
    const float* enc  = (const float*)d_in[1];
    const int*   mask = (const int*)d_in[2];
    const float* Wd   = (const float*)d_in[3];
    const float* We   = (const float*)d_in[4];
    const float* v    = (const float*)d_in[5];

    float* out  = (float*)d_out;
    float* ctx  = out;              // (B, EH)
    float* attn = out + BB * EHH;   // (B, S)

    char* ws = (char*)d_ws;
    float*          dp8    = (float*)ws;                          // 256 KB
    float*          energy = (float*)(ws + (256 << 10));          // 512 KB
    unsigned short* Wpack  = (unsigned short*)(ws + (768 << 10)); // 256 KB
    float*          pctx   = (float*)(ws + (1 << 20));            // 4 MB
    float2*         ml     = (float2*)(ws + (6 << 20));           // 16 KB

    k_prologue<<<384, 256, 0, stream>>>(We, h, Wd, Wpack, dp8);
    k_energy_mfma<<<BB * SS / 64, 512, 0, stream>>>(enc, Wpack, dp8, v, mask,
                                                    energy, pctx, ml);
    k_final<<<dim3(BB, 4), 512, 0, stream>>>(energy, mask, ml, pctx, attn, ctx);
}